// Round 5
// baseline (227.671 us; speedup 1.0000x reference)
//
#include <hip/hip_runtime.h>
#include <hip/hip_fp16.h>

// QuantumRegressionModel: 16-qubit statevector, 3 layers x (16 rotations + CNOT chain),
// PauliZ features + linear head. Batch 64, DIM 65536.
//
// Reductions (verified in rounds 2-4):
//  * Rotations in a layer commute -> split wires {6..15} (kP) and {0..5} (kQ).
//  * CNOT chain == Gray gather psi'[j] = psi[j ^ (j>>1)] -> folded into next kP's loads.
//  * Features on pre-perm state via suffix-parity signs -> fused into final kQ.
//  * fp16 interleaved (re,im) intermediate state, fp32 compute (absmax 6e-5 << 3.9e-4).
//
// Round-5 change: kQ/kQF rebuilt with an LDS transpose. Round-4 kQ issued 64B segments
// at 4KB strides (sub-cache-line, channel-hotspotting) -> ~35-40us/pass. Now global I/O
// is wave-uniform-slice + lane-contiguous (256B per wave instr), and the bit-15..10
// locality gates need comes from the LDS transpose (stride-72 padding, ~2-way aliasing).
//
// Wire q <-> amp-index bit (15-q).
// kP: block = m{15..12} x batch; waves = m{11,10}; lanes = m{7..2}; regs k=m{9,8},
//     e=m{1,0} (16B vector I/O). Gates: w6,w7 (k bits), w8..13 (shuffles), w14,w15 (e bits).
// kQ: block = m{9..6} x batch; tile = m{15..10} x m{5..0} (4096 amps, 16KB LDS);
//     regs = m{15..12} (w0..3), shuffles on lane[5:4] = m{11,10} (w4,w5).

struct G8 { float r00,i00,r01,i01,r10,i10,r11,i11; };

__device__ __forceinline__ G8 loadG(const float* __restrict__ p) {
  G8 g;
  g.r00=p[0]; g.i00=p[1]; g.r01=p[2]; g.i01=p[3];
  g.r10=p[4]; g.i10=p[5]; g.r11=p[6]; g.i11=p[7];
  return g;
}

__device__ __forceinline__ void cmul2(const G8& g, float& r0, float& i0, float& r1, float& i1) {
  const float nr0 = g.r00*r0 - g.i00*i0 + g.r01*r1 - g.i01*i1;
  const float ni0 = g.r00*i0 + g.i00*r0 + g.r01*i1 + g.i01*r1;
  const float nr1 = g.r10*r0 - g.i10*i0 + g.r11*r1 - g.i11*i1;
  const float ni1 = g.r10*i0 + g.i10*r0 + g.r11*i1 + g.i11*r1;
  r0=nr0; i0=ni0; r1=nr1; i1=ni1;
}

union HU { uint4 u; __half2 h[4]; };
union HS { unsigned int u; __half2 h; };

// Build 48 fused unitaries U = Rz(tz)Ry(ty)Rx(tx); zero feats accumulator.
__global__ void kPrep(const float* __restrict__ vp, float* __restrict__ U,
                      float* __restrict__ feats) {
  const int i = threadIdx.x;
  if (i < 48) {
    const float tx = vp[i*6+0], ty = vp[i*6+1], tz = vp[i*6+2];
    float sx, cx, sy, cy, sz, cz;
    sincosf(0.5f*tx, &sx, &cx);
    sincosf(0.5f*ty, &sy, &cy);
    sincosf(0.5f*tz, &sz, &cz);
    const float m00r = cy*cx,  m00i = sy*sx;
    const float m01r = -sy*cx, m01i = -cy*sx;
    const float m10r = sy*cx,  m10i = -cy*sx;
    const float m11r = cy*cx,  m11i = -sy*sx;
    float* o = U + i*8;
    o[0] = cz*m00r + sz*m00i;  o[1] = cz*m00i - sz*m00r;
    o[2] = cz*m01r + sz*m01i;  o[3] = cz*m01i - sz*m01r;
    o[4] = cz*m10r - sz*m10i;  o[5] = cz*m10i + sz*m10r;
    o[6] = cz*m11r - sz*m11i;  o[7] = cz*m11i + sz*m11r;
  }
  for (int j = i; j < 1024; j += 64) feats[j] = 0.f;
}

// kP: wires 6..15 (bits 9..0), 16 amps/thread, no LDS/barriers. (Unchanged from round 4.)
template<int GATHER, int IN32>
__global__ void __launch_bounds__(256) kP(const float* __restrict__ sr, const float* __restrict__ si,
                                          const __half2* __restrict__ s16,
                                          __half2* __restrict__ d16,
                                          const float* __restrict__ Ul) {
  const int t = threadIdx.x;
  const int lane = t & 63;
  const int wv = t >> 6;                         // m{11,10}
  const int b = blockIdx.x >> 4;
  const int tile = blockIdx.x & 15;              // m{15..12}
  const size_t bb = (size_t)b << 16;
  const int hi = (tile << 12) | (wv << 10) | (lane << 2);
  float xr[16], xi[16];                          // a = k*4 + e

  if constexpr (IN32) {
    #pragma unroll
    for (int k = 0; k < 4; ++k) {
      const int j = hi | (k << 8);
      const float4 vr = *(const float4*)(sr + bb + j);
      const float4 vi = *(const float4*)(si + bb + j);
      xr[k*4+0]=vr.x; xr[k*4+1]=vr.y; xr[k*4+2]=vr.z; xr[k*4+3]=vr.w;
      xi[k*4+0]=vi.x; xi[k*4+1]=vi.y; xi[k*4+2]=vi.z; xi[k*4+3]=vi.w;
    }
  } else if constexpr (GATHER) {
    const bool sw = lane & 1;                    // j bit 2
    #pragma unroll
    for (int k = 0; k < 4; ++k) {
      const int j = hi | (k << 8);
      const int a4 = (j ^ (j >> 1)) & ~3;        // source 4-amp window
      HU u; u.u = *(const uint4*)(s16 + bb + a4);
      const float2 f0 = __half22float2(u.h[sw ? 2 : 0]);
      const float2 f1 = __half22float2(u.h[sw ? 3 : 1]);
      const float2 f2 = __half22float2(u.h[sw ? 1 : 3]);
      const float2 f3 = __half22float2(u.h[sw ? 0 : 2]);
      xr[k*4+0]=f0.x; xi[k*4+0]=f0.y;
      xr[k*4+1]=f1.x; xi[k*4+1]=f1.y;
      xr[k*4+2]=f2.x; xi[k*4+2]=f2.y;
      xr[k*4+3]=f3.x; xi[k*4+3]=f3.y;
    }
  } else {
    #pragma unroll
    for (int k = 0; k < 4; ++k) {
      HU u; u.u = *(const uint4*)(s16 + bb + (hi | (k << 8)));
      #pragma unroll
      for (int e = 0; e < 4; ++e) {
        const float2 f = __half22float2(u.h[e]);
        xr[k*4+e]=f.x; xi[k*4+e]=f.y;
      }
    }
  }

  { // w6 on m9 (k bit 1)
    const G8 U = loadG(Ul + 6*8);
    #pragma unroll
    for (int e = 0; e < 4; ++e) {
      cmul2(U, xr[0+e], xi[0+e], xr[8+e],  xi[8+e]);
      cmul2(U, xr[4+e], xi[4+e], xr[12+e], xi[12+e]);
    }
  }
  { // w7 on m8 (k bit 0)
    const G8 U = loadG(Ul + 7*8);
    #pragma unroll
    for (int e = 0; e < 4; ++e) {
      cmul2(U, xr[0+e], xi[0+e], xr[4+e],  xi[4+e]);
      cmul2(U, xr[8+e], xi[8+e], xr[12+e], xi[12+e]);
    }
  }

  // w8..w13 on lane bits 5..0 (m bits 7..2): shuffle gates.
  #pragma unroll
  for (int g = 0; g < 6; ++g) {
    const int lb = 5 - g;
    const int mask = 1 << lb;
    const G8 U = loadG(Ul + (8 + g)*8);
    const bool hib = (lane >> lb) & 1;
    const float ar = hib ? U.r11 : U.r00, ai = hib ? U.i11 : U.i00;
    const float br = hib ? U.r10 : U.r01, bi = hib ? U.i10 : U.i01;
    #pragma unroll
    for (int a = 0; a < 16; ++a) {
      const float pr  = __shfl_xor(xr[a], mask);
      const float pim = __shfl_xor(xi[a], mask);
      const float nr = ar*xr[a] - ai*xi[a] + br*pr - bi*pim;
      const float ni = ar*xi[a] + ai*xr[a] + br*pim + bi*pr;
      xr[a] = nr; xi[a] = ni;
    }
  }

  { // w14 on m1 (e bit 1)
    const G8 U = loadG(Ul + 14*8);
    #pragma unroll
    for (int k = 0; k < 4; ++k) {
      cmul2(U, xr[k*4+0], xi[k*4+0], xr[k*4+2], xi[k*4+2]);
      cmul2(U, xr[k*4+1], xi[k*4+1], xr[k*4+3], xi[k*4+3]);
    }
  }
  { // w15 on m0 (e bit 0)
    const G8 U = loadG(Ul + 15*8);
    #pragma unroll
    for (int k = 0; k < 4; ++k) {
      cmul2(U, xr[k*4+0], xi[k*4+0], xr[k*4+1], xi[k*4+1]);
      cmul2(U, xr[k*4+2], xi[k*4+2], xr[k*4+3], xi[k*4+3]);
    }
  }

  #pragma unroll
  for (int k = 0; k < 4; ++k) {
    HU u;
    u.h[0] = __floats2half2_rn(xr[k*4+0], xi[k*4+0]);
    u.h[1] = __floats2half2_rn(xr[k*4+1], xi[k*4+1]);
    u.h[2] = __floats2half2_rn(xr[k*4+2], xi[k*4+2]);
    u.h[3] = __floats2half2_rn(xr[k*4+3], xi[k*4+3]);
    *(uint4*)(d16 + bb + (hi | (k << 8))) = u.u;
  }
}

#define QSTRIDE 72   // LDS row stride (words) for 64-slot rows: breaks 64-word bank cycle

// Gate body for kQ/kQF: w0..3 on reg bits 3..0 (m15..m12), w4,w5 on lane bits 5,4.
__device__ __forceinline__ void kq_gates(float* xr, float* xi, int lane,
                                         const float* __restrict__ Ul) {
  #pragma unroll
  for (int g = 0; g < 4; ++g) {
    const int kb = 3 - g;
    const G8 U = loadG(Ul + g*8);
    #pragma unroll
    for (int p = 0; p < 8; ++p) {
      const int i0 = ((p >> kb) << (kb + 1)) | (p & ((1 << kb) - 1));
      const int i1 = i0 | (1 << kb);
      cmul2(U, xr[i0], xi[i0], xr[i1], xi[i1]);
    }
  }
  #pragma unroll
  for (int g = 0; g < 2; ++g) {
    const int lb = 5 - g;
    const int mask = 1 << lb;
    const G8 U = loadG(Ul + (4 + g)*8);
    const bool hib = (lane >> lb) & 1;
    const float ar = hib ? U.r11 : U.r00, ai = hib ? U.i11 : U.i00;
    const float br = hib ? U.r10 : U.r01, bi = hib ? U.i10 : U.i01;
    #pragma unroll
    for (int a = 0; a < 16; ++a) {
      const float pr  = __shfl_xor(xr[a], mask);
      const float pim = __shfl_xor(xi[a], mask);
      const float nr = ar*xr[a] - ai*xi[a] + br*pr - bi*pim;
      const float ni = ar*xi[a] + ai*xr[a] + br*pim + bi*pr;
      xr[a] = nr; xi[a] = ni;
    }
  }
}

// kQ: wires 0..5, LDS-transpose version, in-place.
// Block = batch x m{9..6}; tile = m{15..10} (slice S) x m{5..0} (lo). 4096 amps, 16KB LDS.
__global__ void __launch_bounds__(256) kQ(__half2* __restrict__ st,
                                          const float* __restrict__ Ul) {
  __shared__ unsigned int lds[64 * QSTRIDE];
  const int t = threadIdx.x;
  const int lane = t & 63, wv = t >> 6;
  const int b = blockIdx.x >> 4, mid = blockIdx.x & 15;
  const size_t base = ((size_t)b << 16) | (mid << 6);
  // Load: wave-uniform slice, lane-contiguous 256B per wave instr.
  #pragma unroll
  for (int i = 0; i < 16; ++i) {
    const int L = i * 256 + t;
    const int S = L >> 6, lo6 = L & 63;
    lds[S * QSTRIDE + lo6] = *(const unsigned int*)(st + (base | (S << 10) | lo6));
  }
  __syncthreads();
  // Transpose read: regs r = m{15..12}; lane[5:4] = m{11,10}; wave = m{5,4}; lane[3:0] = m{3..0}.
  const int shi = lane >> 4;                  // m{11,10}
  const int lo  = (wv << 4) | (lane & 15);    // m{5,4} | m{3..0}
  float xr[16], xi[16];
  #pragma unroll
  for (int r = 0; r < 16; ++r) {
    HS u; u.u = lds[((r << 2) | shi) * QSTRIDE + lo];
    const float2 f = __half22float2(u.h);
    xr[r] = f.x; xi[r] = f.y;
  }
  __syncthreads();
  kq_gates(xr, xi, lane, Ul);
  #pragma unroll
  for (int r = 0; r < 16; ++r) {
    HS u; u.h = __floats2half2_rn(xr[r], xi[r]);
    lds[((r << 2) | shi) * QSTRIDE + lo] = u.u;
  }
  __syncthreads();
  #pragma unroll
  for (int i = 0; i < 16; ++i) {
    const int L = i * 256 + t;
    const int S = L >> 6, lo6 = L & 63;
    *(unsigned int*)(st + (base | (S << 10) | lo6)) = lds[S * QSTRIDE + lo6];
  }
}

// kQF: final-layer kQ + fused PauliZ features (pending perm folded via suffix-parity signs).
__global__ void __launch_bounds__(256) kQF(const __half2* __restrict__ st,
                                           const float* __restrict__ Ul,
                                           float* __restrict__ feats) {
  __shared__ unsigned int lds[64 * QSTRIDE];
  __shared__ float sf[64];
  const int t = threadIdx.x;
  const int lane = t & 63, wv = t >> 6;
  const int b = blockIdx.x >> 4, mid = blockIdx.x & 15;
  const size_t base = ((size_t)b << 16) | (mid << 6);
  #pragma unroll
  for (int i = 0; i < 16; ++i) {
    const int L = i * 256 + t;
    const int S = L >> 6, lo6 = L & 63;
    lds[S * QSTRIDE + lo6] = *(const unsigned int*)(st + (base | (S << 10) | lo6));
  }
  __syncthreads();
  const int shi = lane >> 4;
  const int lo  = (wv << 4) | (lane & 15);
  float xr[16], xi[16];
  #pragma unroll
  for (int r = 0; r < 16; ++r) {
    HS u; u.u = lds[((r << 2) | shi) * QSTRIDE + lo];
    const float2 f = __half22float2(u.h);
    xr[r] = f.x; xi[r] = f.y;
  }
  kq_gates(xr, xi, lane, Ul);
  // r = m{15..12}: suffix-parity classes over reg bits.
  float T15=0.f, T14=0.f, T13=0.f, T12=0.f;
  #pragma unroll
  for (int r = 0; r < 16; ++r) {
    const float p = xr[r]*xr[r] + xi[r]*xi[r];
    const int b3=(r>>3)&1, b2=(r>>2)&1, b1=(r>>1)&1, b0=r&1;
    T15 += b3 ? -p : p;
    T14 += (b3^b2) ? -p : p;
    T13 += (b3^b2^b1) ? -p : p;
    T12 += (b3^b2^b1^b0) ? -p : p;
  }
  int w = (shi << 10) | (mid << 6) | lo;       // thread-constant m bits 11..0
  w ^= w >> 1; w ^= w >> 2; w ^= w >> 4; w ^= w >> 8;
  float f[16];
  #pragma unroll
  for (int qq = 0; qq < 16; ++qq) {
    const int c = 15 - qq;
    const float T = (qq == 0) ? T15 : (qq == 1) ? T14 : (qq == 2) ? T13 : T12;
    f[qq] = ((w >> c) & 1) ? -T : T;
  }
  #pragma unroll
  for (int qq = 0; qq < 16; ++qq) {
    float s = f[qq];
    s += __shfl_xor(s, 32); s += __shfl_xor(s, 16); s += __shfl_xor(s, 8);
    s += __shfl_xor(s, 4);  s += __shfl_xor(s, 2);  s += __shfl_xor(s, 1);
    f[qq] = s;
  }
  __syncthreads();
  if ((t & 63) == 0) {
    #pragma unroll
    for (int qq = 0; qq < 16; ++qq) sf[wv*16 + qq] = f[qq];
  }
  __syncthreads();
  if (t < 16) {
    const float s = sf[t] + sf[16 + t] + sf[32 + t] + sf[48 + t];
    atomicAdd(&feats[b*16 + t], s);
  }
}

__global__ void kHead(const float* __restrict__ feats, const float* __restrict__ w,
                      const float* __restrict__ bias, float* __restrict__ out) {
  const int b = threadIdx.x;
  if (b < 64) {
    float v = bias[0];
    #pragma unroll
    for (int q = 0; q < 16; ++q) v += feats[b*16 + q] * w[q];
    out[b] = v;
  }
}

extern "C" void kernel_launch(void* const* d_in, const int* in_sizes, int n_in,
                              void* d_out, int out_size, void* d_ws, size_t ws_size,
                              hipStream_t stream) {
  const float* in_r = (const float*)d_in[0];  // (64, 65536) fp32
  const float* in_i = (const float*)d_in[1];
  const float* vp = (const float*)d_in[2];    // (3,16,6)
  const float* hw = (const float*)d_in[3];    // (1,16)
  const float* hb = (const float*)d_in[4];    // (1,)
  float* out = (float*)d_out;                 // (64,) fp32

  __half2* st0 = (__half2*)d_ws;              // 4,194,304 amps, 16 MB
  __half2* st1 = st0 + 4194304ull;            // 16 MB
  float* Ubuf  = (float*)(st1 + 4194304ull);  // 48*8 floats
  float* feats = Ubuf + 384;                  // 64*16 floats

  kPrep<<<1, 64, 0, stream>>>(vp, Ubuf, feats);
  // layer 0
  kP<0,1><<<1024, 256, 0, stream>>>(in_r, in_i, nullptr, st0, Ubuf + 0*128);
  kQ     <<<1024, 256, 0, stream>>>(st0, Ubuf + 0*128);
  // layer 1 (perm of layer 0 folded into gather-load)
  kP<1,0><<<1024, 256, 0, stream>>>(nullptr, nullptr, st0, st1, Ubuf + 1*128);
  kQ     <<<1024, 256, 0, stream>>>(st1, Ubuf + 1*128);
  // layer 2
  kP<1,0><<<1024, 256, 0, stream>>>(nullptr, nullptr, st1, st0, Ubuf + 2*128);
  kQF    <<<1024, 256, 0, stream>>>(st0, Ubuf + 2*128, feats);
  kHead<<<1, 64, 0, stream>>>(feats, hw, hb, out);
}